// Round 12
// baseline (385.554 us; speedup 1.0000x reference)
//
#include <hip/hip_runtime.h>
#include <math.h>

// ---- NSA hyperparameters (compile-time, matches reference config) ----
constexpr int kT    = 2048;
constexpr int kHQ   = 16;
constexpr int kD    = 128;
constexpr int kKS   = 32;
constexpr int kST   = 16;
constexpr int kBS   = 64;
constexpr int kM    = (kT - kKS) / kST + 1;   // 127 compressed tokens
constexpr int kNB   = (kT + kBS - 1) / kBS;   // 32 selection blocks
constexpr int kTopN = 16;
constexpr int kNInit = 2;
constexpr int kWIN  = 512;
constexpr float kNEG = -1e30f;
constexpr float kScale = 0.08838834764831845f;      // 128^-0.5
// log2-domain scores: fold log2(e) into q scaling -> bare exp2 everywhere
constexpr float kScaleL2 = kScale * 1.4426950408889634f;

constexpr int kPSt = 72;    // P slab row stride (fp16)
constexpr int kPL  = 136;   // Phase-A p_lds row stride (bf16 shorts)

// ---- shm layout (bytes).  Phase-A p_lds (4352B) overlays PS0+PS1 (dead
// until pass 1).  dump+ml are the wave1->wave0 exchange, reused for the
// sel merge (pass-1 boundary) then the swa merge (post pass 2).
constexpr int kPS0 = 0;      // 2304: wave0 P slab
constexpr int kPS1 = 2304;   // 2304: wave1 P slab
constexpr int kDmp = 4608;   // 4096: osel/oswa exchange (wave1 partials)
constexpr int kMl  = 8704;   // 128: 16 heads x float2 (m,l)
constexpr int kShm = 8832;

typedef __attribute__((ext_vector_type(8))) short short8;
typedef __attribute__((ext_vector_type(4))) short short4v;
typedef __attribute__((ext_vector_type(8))) _Float16 half8;
typedef __attribute__((ext_vector_type(4))) _Float16 half4v;
typedef __attribute__((ext_vector_type(4))) float floatx4;

// RNE float -> bf16 bits
__device__ inline short f2bf(float x) {
    unsigned u = __float_as_uint(x);
    unsigned r = (u + 0x7fffu + ((u >> 16) & 1u)) >> 16;
    return (short)r;
}
__device__ inline float b2f(short h) {
    return __uint_as_float(((unsigned)(unsigned short)h) << 16);
}

// ---------------------------------------------------------------------
// K1: FRAGMENT-ORDERED staging (R9-proven, unchanged).
// ---------------------------------------------------------------------
__global__ __launch_bounds__(256) void k_stage(
        const float* __restrict__ k, const float* __restrict__ v,
        short* __restrict__ kb2, _Float16* __restrict__ vt2,
        short* __restrict__ ck2h, short* __restrict__ ck2l,
        short* __restrict__ cv2) {
    const int bid = blockIdx.x;
    const int tid = threadIdx.x;
    __shared__ _Float16 vls[64 * 132];

    if (bid < 32) {
        const int b = bid;
        #pragma unroll
        for (int p = 0; p < 4; ++p) {
            const int idx = p * 256 + tid;          // 0..1023 = g*64 + lane
            const int g = idx >> 6;                  // kt*4 + c
            const int lane2 = idx & 63;
            const int kt = g >> 2, c = g & 3;
            const int l15v = lane2 & 15, quadv = lane2 >> 4;
            const float* src = k + (size_t)(b * 64 + kt * 16 + l15v) * kD + c * 32 + quadv * 8;
            const float4 f0 = *(const float4*)(src);
            const float4 f1 = *(const float4*)(src + 4);
            short8 s;
            s[0] = f2bf(f0.x); s[1] = f2bf(f0.y); s[2] = f2bf(f0.z); s[3] = f2bf(f0.w);
            s[4] = f2bf(f1.x); s[5] = f2bf(f1.y); s[6] = f2bf(f1.z); s[7] = f2bf(f1.w);
            *(short8*)(kb2 + ((size_t)b * 1024 + idx) * 8) = s;
        }
    } else if (bid < 64) {
        const int b = bid - 32;
        #pragma unroll
        for (int p = 0; p < 8; ++p) {
            const int idx = p * 256 + tid;   // 2048 float4-slots
            const int r = idx >> 5;
            const int d4 = (idx & 31) * 4;
            const float4 f = *(const float4*)(v + (size_t)(b * 64 + r) * kD + d4);
            _Float16* dst = &vls[r * 132 + d4];
            dst[0] = (_Float16)f.x; dst[1] = (_Float16)f.y;
            dst[2] = (_Float16)f.z; dst[3] = (_Float16)f.w;
        }
        __syncthreads();
        #pragma unroll
        for (int p = 0; p < 4; ++p) {
            const int idx = p * 256 + tid;   // g*64 + lane
            const int g = idx >> 6;          // n8*2 + kc
            const int lane2 = idx & 63;
            const int n8 = g >> 1, kc = g & 1;
            const int l15v = lane2 & 15, quadv = lane2 >> 4;
            half8 h;
            #pragma unroll
            for (int j = 0; j < 8; ++j) {
                const int col = kc * 32 + quadv * 8 + j;
                const int w = (col & 3) * 16 + (col >> 2);
                h[j] = vls[w * 132 + n8 * 16 + l15v];
            }
            *(half8*)(vt2 + ((size_t)b * 1024 + idx) * 8) = h;
        }
    } else {
        const int m = (bid - 64) * 2 + (tid >> 7);   // 0..127
        const int d = tid & 127;
        float sk = 0.f, sv = 0.f;
        if (m < kM) {
            const int base = m * kST;
            #pragma unroll
            for (int i = 0; i < kKS; ++i) {
                sk += k[(size_t)(base + i) * kD + d];
                sv += v[(size_t)(base + i) * kD + d];
            }
            sk *= (1.0f / kKS);
            sv *= (1.0f / kKS);
        }
        const short hi = f2bf(sk);
        const short lo = f2bf(sk - b2f(hi));
        const int mt = m >> 4, l15m = m & 15;
        const int c = d >> 5, quadv = (d >> 3) & 3, j = d & 7;
        const int kdst = ((mt * 4 + c) * 64 + quadv * 16 + l15m) * 8 + j;
        ck2h[kdst] = hi;
        ck2l[kdst] = lo;
        const int nt = d >> 4, l15d = d & 15;
        const int pc = (m & 64) + 4 * (m & 15) + ((m & 63) >> 4);
        const int cp = pc >> 5, quadp = (pc >> 3) & 3, jp = pc & 7;
        cv2[((nt * 4 + cp) * 64 + quadp * 16 + l15d) * 8 + jp] = f2bf(sv);
    }
}

// ---------------------------------------------------------------------
// Fused NSA, 2 waves/query (block=128, grid=T, t=2047-bid).
// R12: LDS diet 19.4KB -> ~9.2KB via incremental merge-to-global:
//  - Phase A writes w0*ocmp DIRECTLY to out (no ocst stash).
//  - SEL merged at the pass-1/pass-2 boundary: wave1 dumps osel+stats
//    (region reused later for oswa), wave0 (osel in regs) LSE-merges
//    and RMWs out += w1*selM.  SWA merged the same way after pass 2.
// With VGPR<=64 (launch_bounds(128,8); R11 proved 64 achievable) the
// 9.2KB LDS permits 16 blocks/CU = 8 waves/SIMD (was 4, LDS-bound).
// ---------------------------------------------------------------------
__global__ __launch_bounds__(128, 8) void k_nsa(
        const float* __restrict__ q, const float* __restrict__ cw,
        const short* __restrict__ ck2h, const short* __restrict__ ck2l,
        const short* __restrict__ cv2, const short* __restrict__ kb2,
        const _Float16* __restrict__ vt2, float* __restrict__ out) {
    const int tid = threadIdx.x;
    const int wave = tid >> 6;
    const int lane = tid & 63;
    const int l15 = lane & 15;
    const int quad = lane >> 4;
    const int t = kT - 1 - blockIdx.x;   // LPT: heavy first

    __shared__ float sp[kNB];
    __shared__ unsigned selm_s;
    __shared__ __align__(16) char shm[kShm];

    _Float16* const PSme = (_Float16*)(shm + (wave ? kPS1 : kPS0));

    // ---- q head=l15, scaled by kScale*log2e -> bf16 hi (both waves) ----
    short8 qh[4];
    {
        const float* qp = q + ((size_t)t * kHQ + l15) * kD + quad * 8;
        #pragma unroll
        for (int c = 0; c < 4; ++c) {
            const float4 f0 = *(const float4*)(qp + c * 32);
            const float4 f1 = *(const float4*)(qp + c * 32 + 4);
            const float xs[8] = {f0.x, f0.y, f0.z, f0.w, f1.x, f1.y, f1.z, f1.w};
            #pragma unroll
            for (int j = 0; j < 8; ++j) qh[c][j] = f2bf(xs[j] * kScaleL2);
        }
    }

    const int nvalid = (t >= kKS - 1) ? min(kM, (t - (kKS - 1)) / kST + 1) : 0;
    const int cur = t >> 6;

    // ================= Phase A (wave0 only), log2-domain =================
    if (wave == 0) {
        // lo-half of q built locally (dies with Phase A)
        short8 ql[4];
        {
            const float* qp = q + ((size_t)t * kHQ + l15) * kD + quad * 8;
            #pragma unroll
            for (int c = 0; c < 4; ++c) {
                const float4 f0 = *(const float4*)(qp + c * 32);
                const float4 f1 = *(const float4*)(qp + c * 32 + 4);
                const float xs[8] = {f0.x, f0.y, f0.z, f0.w, f1.x, f1.y, f1.z, f1.w};
                #pragma unroll
                for (int j = 0; j < 8; ++j)
                    ql[c][j] = f2bf(xs[j] * kScaleL2 - b2f(qh[c][j]));
            }
        }
        short* const p_lds = (short*)shm;   // 4352 B, overlays PS0+PS1 (dead)
        floatx4 sacc[8];
        #pragma unroll
        for (int mt = 0; mt < 8; ++mt) {
            sacc[mt] = (floatx4){0, 0, 0, 0};
            #pragma unroll
            for (int c = 0; c < 4; ++c) {
                const short8 Ah = *(const short8*)(ck2h + ((mt * 4 + c) * 64 + lane) * 8);
                const short8 Al = *(const short8*)(ck2l + ((mt * 4 + c) * 64 + lane) * 8);
                sacc[mt] = __builtin_amdgcn_mfma_f32_16x16x32_bf16(Ah, qh[c], sacc[mt], 0, 0, 0);
                sacc[mt] = __builtin_amdgcn_mfma_f32_16x16x32_bf16(Ah, ql[c], sacc[mt], 0, 0, 0);
                sacc[mt] = __builtin_amdgcn_mfma_f32_16x16x32_bf16(Al, qh[c], sacc[mt], 0, 0, 0);
            }
        }
        // mask + max (sacc reused in place: scores -> exps -> probs)
        float mx = kNEG;
        #pragma unroll
        for (int mt = 0; mt < 8; ++mt)
            #pragma unroll
            for (int r = 0; r < 4; ++r) {
                const int m = mt * 16 + quad * 4 + r;
                const float s = (m < nvalid) ? sacc[mt][r] : kNEG;
                sacc[mt][r] = s;
                mx = fmaxf(mx, s);
            }
        mx = fmaxf(mx, __shfl_xor(mx, 16));
        mx = fmaxf(mx, __shfl_xor(mx, 32));
        float sum = 0.f;
        #pragma unroll
        for (int mt = 0; mt < 8; ++mt)
            #pragma unroll
            for (int r = 0; r < 4; ++r) {
                const int m = mt * 16 + quad * 4 + r;
                const float ev = (m < nvalid) ? exp2f(sacc[mt][r] - mx) : 0.f;
                sacc[mt][r] = ev;
                sum += ev;
            }
        sum += __shfl_xor(sum, 16);
        sum += __shfl_xor(sum, 32);
        const float inv = (nvalid > 0) ? (1.f / sum) : 0.f;

        float Z[8], Y[8];
        #pragma unroll
        for (int mt = 0; mt < 8; ++mt) {
            const float p0 = sacc[mt][0] * inv, p1 = sacc[mt][1] * inv;
            const float p2 = sacc[mt][2] * inv, p3 = sacc[mt][3] * inv;
            sacc[mt][0] = p0; sacc[mt][1] = p1; sacc[mt][2] = p2; sacc[mt][3] = p3;
            Z[mt] = p0 + p1 + p2 + 0.5f * p3;
            Y[mt] = p3;
        }
        #pragma unroll
        for (int g = 0; g < 2; ++g)
            #pragma unroll
            for (int r = 0; r < 4; ++r) {
                short4v s4;
                s4[0] = f2bf(sacc[4 * g + 0][r]); s4[1] = f2bf(sacc[4 * g + 1][r]);
                s4[2] = f2bf(sacc[4 * g + 2][r]); s4[3] = f2bf(sacc[4 * g + 3][r]);
                *(short4v*)&p_lds[l15 * kPL + g * 64 + 16 * quad + 4 * r] = s4;
            }
        #pragma unroll
        for (int mt = 0; mt < 8; ++mt) {
            #pragma unroll
            for (int o = 1; o <= 8; o <<= 1) {
                Z[mt] += __shfl_xor(Z[mt], o, 16);
                Y[mt] += __shfl_xor(Y[mt], o, 16);
            }
        }
        const int srcl = ((quad + 3) & 3) * 16 + l15;
        #pragma unroll
        for (int mt = 0; mt < 8; ++mt) {
            const float up  = __shfl(Y[mt], srcl);
            const float upm = __shfl(Y[(mt + 7) & 7], srcl);
            const float pv = quad ? up : (mt ? upm : 0.f);
            const int b = 4 * mt + quad;
            float x = Z[mt] + 0.5f * pv;
            if (b > cur) x = kNEG;
            if (b < kNInit || b == cur) x = 1e30f;
            if (l15 == 0) sp[b] = x;
        }
        bool selp = false;
        if (lane < kNB) {
            const float xv = sp[lane];
            int rank = 0;
            #pragma unroll
            for (int b2 = 0; b2 < kNB; ++b2) {
                const float y = sp[b2];
                rank += (y > xv || (y == xv && b2 < lane)) ? 1 : 0;
            }
            selp = rank < kTopN;
        }
        const unsigned sm = (unsigned)__ballot(selp);
        if (lane == 0) selm_s = sm;

        // cmp PV -> out = w0*ocmp directly (no LDS stash; same-wave RMW later)
        short8 ap[4];
        #pragma unroll
        for (int c = 0; c < 4; ++c)
            ap[c] = *(const short8*)&p_lds[l15 * kPL + c * 32 + quad * 8];
        float w0h[4];
        #pragma unroll
        for (int r = 0; r < 4; ++r) {
            const int h = quad * 4 + r;
            const float cwa = cw[((size_t)t * kHQ + h) * 3 + 0];
            w0h[r] = 1.f / (1.f + __expf(-cwa));
        }
        #pragma unroll
        for (int nt = 0; nt < 8; ++nt) {
            floatx4 oc = (floatx4){0, 0, 0, 0};
            #pragma unroll
            for (int c = 0; c < 4; ++c) {
                const short8 bv = *(const short8*)(cv2 + ((nt * 4 + c) * 64 + lane) * 8);
                oc = __builtin_amdgcn_mfma_f32_16x16x32_bf16(ap[c], bv, oc, 0, 0, 0);
            }
            #pragma unroll
            for (int r = 0; r < 4; ++r) {
                const int h = quad * 4 + r;
                out[((size_t)t * kHQ + h) * kD + nt * 16 + l15] = w0h[r] * oc[r];
            }
        }
    }
    __syncthreads();   // bar0: selm visible; Phase-A LDS dead before slabs reuse

    const unsigned selm = selm_s;
    const int lob = max(0, (t - (kWIN - 1)) >> 6);
    const unsigned lm = 0xFFFFFFFFu >> (31 - cur);

    // ================== PASS 1: SEL (osel in regs) ==================
    {
        float mS = kNEG, lS = 0.f;
        floatx4 osel[8];
        #pragma unroll
        for (int n8 = 0; n8 < 8; ++n8) osel[n8] = (floatx4){0, 0, 0, 0};

        unsigned a = selm & lm;
        int bi = 0;
        while (a) {
            const int b = __builtin_ctz(a);
            a &= a - 1u;
            const bool mine = ((bi & 1) != wave);
            ++bi;
            if (!mine) continue;

            const short* kbb = kb2 + ((size_t)b * 1024 + lane) * 8;
            floatx4 acc[4];
            {
                short8 kreg[2][4];
                #pragma unroll
                for (int kt = 0; kt < 2; ++kt)
                    #pragma unroll
                    for (int c = 0; c < 4; ++c)
                        kreg[kt][c] = *(const short8*)(kbb + (kt * 4 + c) * 512);
                #pragma unroll
                for (int kt = 0; kt < 2; ++kt) {
                    acc[kt] = (floatx4){0, 0, 0, 0};
                    #pragma unroll
                    for (int c = 0; c < 4; ++c)
                        acc[kt] = __builtin_amdgcn_mfma_f32_16x16x32_bf16(kreg[kt][c], qh[c], acc[kt], 0, 0, 0);
                }
                #pragma unroll
                for (int kt = 0; kt < 2; ++kt)
                    #pragma unroll
                    for (int c = 0; c < 4; ++c)
                        kreg[kt][c] = *(const short8*)(kbb + ((kt + 2) * 4 + c) * 512);
                #pragma unroll
                for (int kt = 0; kt < 2; ++kt) {
                    acc[kt + 2] = (floatx4){0, 0, 0, 0};
                    #pragma unroll
                    for (int c = 0; c < 4; ++c)
                        acc[kt + 2] = __builtin_amdgcn_mfma_f32_16x16x32_bf16(kreg[kt][c], qh[c], acc[kt + 2], 0, 0, 0);
                }
            }

            const int kbo = b * kBS + quad * 4;
            float bm = kNEG;
            #pragma unroll
            for (int kt = 0; kt < 4; ++kt)
                #pragma unroll
                for (int r = 0; r < 4; ++r) {
                    const int key = kbo + kt * 16 + r;
                    if (key <= t) bm = fmaxf(bm, acc[kt][r]);
                }
            bm = fmaxf(bm, __shfl_xor(bm, 16));
            bm = fmaxf(bm, __shfl_xor(bm, 32));
            const float mn = fmaxf(mS, bm);
            const float al = exp2f(mS - mn);

            float sum = 0.f;
            #pragma unroll
            for (int r = 0; r < 4; ++r) {
                half4v hs;
                #pragma unroll
                for (int kt = 0; kt < 4; ++kt) {
                    const int key = kbo + kt * 16 + r;
                    const float e0 = (key <= t) ? exp2f(acc[kt][r] - mn) : 0.f;
                    sum += e0;
                    hs[kt] = (_Float16)e0;
                }
                *(half4v*)&PSme[l15 * kPSt + 16 * quad + 4 * r] = hs;
            }
            sum += __shfl_xor(sum, 16);
            sum += __shfl_xor(sum, 32);
            lS = lS * al + sum; mS = mn;

            float alh[4];
            #pragma unroll
            for (int r = 0; r < 4; ++r) alh[r] = __shfl(al, quad * 4 + r);
            const half8 ap0 = *(const half8*)&PSme[l15 * kPSt + quad * 8];
            const half8 ap1 = *(const half8*)&PSme[l15 * kPSt + 32 + quad * 8];
            const _Float16* vtb = vt2 + ((size_t)b * 1024 + lane) * 8;
            {
                half8 vr[4][2];
                #pragma unroll
                for (int n8 = 0; n8 < 4; ++n8) {
                    vr[n8][0] = *(const half8*)(vtb + (n8 * 2 + 0) * 512);
                    vr[n8][1] = *(const half8*)(vtb + (n8 * 2 + 1) * 512);
                }
                #pragma unroll
                for (int n8 = 0; n8 < 4; ++n8) {
                    #pragma unroll
                    for (int r = 0; r < 4; ++r) osel[n8][r] *= alh[r];
                    osel[n8] = __builtin_amdgcn_mfma_f32_16x16x32_f16(ap0, vr[n8][0], osel[n8], 0, 0, 0);
                    osel[n8] = __builtin_amdgcn_mfma_f32_16x16x32_f16(ap1, vr[n8][1], osel[n8], 0, 0, 0);
                }
                #pragma unroll
                for (int n8 = 0; n8 < 4; ++n8) {
                    vr[n8][0] = *(const half8*)(vtb + ((n8 + 4) * 2 + 0) * 512);
                    vr[n8][1] = *(const half8*)(vtb + ((n8 + 4) * 2 + 1) * 512);
                }
                #pragma unroll
                for (int n8 = 0; n8 < 4; ++n8) {
                    #pragma unroll
                    for (int r = 0; r < 4; ++r) osel[n8 + 4][r] *= alh[r];
                    osel[n8 + 4] = __builtin_amdgcn_mfma_f32_16x16x32_f16(ap0, vr[n8][0], osel[n8 + 4], 0, 0, 0);
                    osel[n8 + 4] = __builtin_amdgcn_mfma_f32_16x16x32_f16(ap1, vr[n8][1], osel[n8 + 4], 0, 0, 0);
                }
            }
        }

        // ---- SEL exchange + merge (dump region freed before pass-2 use) ----
        if (wave == 1) {
            short* const dmp = (short*)(shm + kDmp);
            #pragma unroll
            for (int n8 = 0; n8 < 8; ++n8) {
                short4v s4;
                #pragma unroll
                for (int r = 0; r < 4; ++r) s4[r] = f2bf(osel[n8][r]);
                *(short4v*)&dmp[lane * 32 + n8 * 4] = s4;
            }
            if (quad == 0) ((float2*)(shm + kMl))[l15] = make_float2(mS, lS);
        }
        __syncthreads();   // barA: wave1 partials visible
        if (wave == 0) {
            const short* const ox1 = (const short*)(shm + kDmp);
            const float2* const ml1 = (const float2*)(shm + kMl);
            #pragma unroll
            for (int r = 0; r < 4; ++r) {
                const int h = quad * 4 + r;
                const float m0 = __shfl(mS, h), l0 = __shfl(lS, h);
                const float2 s1 = ml1[h];
                const float mM = fmaxf(m0, s1.x);
                const float c0 = exp2f(m0 - mM);
                const float c1 = exp2f(s1.x - mM);
                const float li = 1.f / (l0 * c0 + s1.y * c1);
                const float cwb = cw[((size_t)t * kHQ + h) * 3 + 1];
                const float w1 = 1.f / (1.f + __expf(-cwb));
                float* op = out + ((size_t)t * kHQ + h) * kD + l15;
                #pragma unroll
                for (int n8 = 0; n8 < 8; ++n8) {
                    const float sM = (osel[n8][r] * c0 + b2f(ox1[lane * 32 + n8 * 4 + r]) * c1) * li;
                    op[n8 * 16] += w1 * sM;
                }
            }
        }
    }

    // ================== PASS 2: SWA (oswa in regs) ==================
    float mW = kNEG, lW = 0.f;
    floatx4 oswa[8];
    #pragma unroll
    for (int n8 = 0; n8 < 8; ++n8) oswa[n8] = (floatx4){0, 0, 0, 0};
    {
        unsigned a = lm & ~((1u << lob) - 1u);
        int bi = 0;
        while (a) {
            const int b = __builtin_ctz(a);
            a &= a - 1u;
            const bool mine = ((bi & 1) != wave);
            ++bi;
            if (!mine) continue;

            const short* kbb = kb2 + ((size_t)b * 1024 + lane) * 8;
            floatx4 acc[4];
            {
                short8 kreg[2][4];
                #pragma unroll
                for (int kt = 0; kt < 2; ++kt)
                    #pragma unroll
                    for (int c = 0; c < 4; ++c)
                        kreg[kt][c] = *(const short8*)(kbb + (kt * 4 + c) * 512);
                #pragma unroll
                for (int kt = 0; kt < 2; ++kt) {
                    acc[kt] = (floatx4){0, 0, 0, 0};
                    #pragma unroll
                    for (int c = 0; c < 4; ++c)
                        acc[kt] = __builtin_amdgcn_mfma_f32_16x16x32_bf16(kreg[kt][c], qh[c], acc[kt], 0, 0, 0);
                }
                #pragma unroll
                for (int kt = 0; kt < 2; ++kt)
                    #pragma unroll
                    for (int c = 0; c < 4; ++c)
                        kreg[kt][c] = *(const short8*)(kbb + ((kt + 2) * 4 + c) * 512);
                #pragma unroll
                for (int kt = 0; kt < 2; ++kt) {
                    acc[kt + 2] = (floatx4){0, 0, 0, 0};
                    #pragma unroll
                    for (int c = 0; c < 4; ++c)
                        acc[kt + 2] = __builtin_amdgcn_mfma_f32_16x16x32_bf16(kreg[kt][c], qh[c], acc[kt + 2], 0, 0, 0);
                }
            }

            const int kbo = b * kBS + quad * 4;
            float bm = kNEG;
            #pragma unroll
            for (int kt = 0; kt < 4; ++kt)
                #pragma unroll
                for (int r = 0; r < 4; ++r) {
                    const int key = kbo + kt * 16 + r;
                    if (key <= t && (t - key) < kWIN) bm = fmaxf(bm, acc[kt][r]);
                }
            bm = fmaxf(bm, __shfl_xor(bm, 16));
            bm = fmaxf(bm, __shfl_xor(bm, 32));
            const float mn = fmaxf(mW, bm);
            const float al = exp2f(mW - mn);

            float sum = 0.f;
            #pragma unroll
            for (int r = 0; r < 4; ++r) {
                half4v hw;
                #pragma unroll
                for (int kt = 0; kt < 4; ++kt) {
                    const int key = kbo + kt * 16 + r;
                    const float e0 = (key <= t && (t - key) < kWIN) ? exp2f(acc[kt][r] - mn) : 0.f;
                    sum += e0;
                    hw[kt] = (_Float16)e0;
                }
                *(half4v*)&PSme[l15 * kPSt + 16 * quad + 4 * r] = hw;
            }
            sum += __shfl_xor(sum, 16);
            sum += __shfl_xor(sum, 32);
            lW = lW * al + sum; mW = mn;

            float alh[4];
            #pragma unroll
            for (int r = 0; r < 4; ++r) alh[r] = __shfl(al, quad * 4 + r);
            const half8 ap0 = *(const half8*)&PSme[l15 * kPSt + quad * 8];
            const half8 ap1 = *(const half8*)&PSme[l15 * kPSt + 32 + quad * 8];
            const _Float16* vtb = vt2 + ((size_t)b * 1024 + lane) * 8;
            {
                half8 vr[4][2];
                #pragma unroll
                for (int n8 = 0; n8 < 4; ++n8) {
                    vr[n8][0] = *(const half8*)(vtb + (n8 * 2 + 0) * 512);
                    vr[n8][1] = *(const half8*)(vtb + (n8 * 2 + 1) * 512);
                }
                #pragma unroll
                for (int n8 = 0; n8 < 4; ++n8) {
                    #pragma unroll
                    for (int r = 0; r < 4; ++r) oswa[n8][r] *= alh[r];
                    oswa[n8] = __builtin_amdgcn_mfma_f32_16x16x32_f16(ap0, vr[n8][0], oswa[n8], 0, 0, 0);
                    oswa[n8] = __builtin_amdgcn_mfma_f32_16x16x32_f16(ap1, vr[n8][1], oswa[n8], 0, 0, 0);
                }
                #pragma unroll
                for (int n8 = 0; n8 < 4; ++n8) {
                    vr[n8][0] = *(const half8*)(vtb + ((n8 + 4) * 2 + 0) * 512);
                    vr[n8][1] = *(const half8*)(vtb + ((n8 + 4) * 2 + 1) * 512);
                }
                #pragma unroll
                for (int n8 = 0; n8 < 4; ++n8) {
                    #pragma unroll
                    for (int r = 0; r < 4; ++r) oswa[n8 + 4][r] *= alh[r];
                    oswa[n8 + 4] = __builtin_amdgcn_mfma_f32_16x16x32_f16(ap0, vr[n8][0], oswa[n8 + 4], 0, 0, 0);
                    oswa[n8 + 4] = __builtin_amdgcn_mfma_f32_16x16x32_f16(ap1, vr[n8][1], oswa[n8 + 4], 0, 0, 0);
                }
            }
        }
    }

    __syncthreads();   // barB: both pass-2 done; wave0's sel reads long done
    if (wave == 1) {
        short* const dmp = (short*)(shm + kDmp);
        #pragma unroll
        for (int n8 = 0; n8 < 8; ++n8) {
            short4v w4;
            #pragma unroll
            for (int r = 0; r < 4; ++r) w4[r] = f2bf(oswa[n8][r]);
            *(short4v*)&dmp[lane * 32 + n8 * 4] = w4;
        }
        if (quad == 0) ((float2*)(shm + kMl))[l15] = make_float2(mW, lW);
    }
    __syncthreads();   // barC: wave1 swa partials visible
    if (wave == 0) {
        const short* const ox1 = (const short*)(shm + kDmp);
        const float2* const ml1 = (const float2*)(shm + kMl);
        #pragma unroll
        for (int r = 0; r < 4; ++r) {
            const int h = quad * 4 + r;
            const float m0 = __shfl(mW, h), l0 = __shfl(lW, h);
            const float2 s1 = ml1[h];
            const float mM = fmaxf(m0, s1.x);
            const float c0 = exp2f(m0 - mM);
            const float c1 = exp2f(s1.x - mM);
            const float li = 1.f / (l0 * c0 + s1.y * c1);
            const float cwc = cw[((size_t)t * kHQ + h) * 3 + 2];
            const float w2 = 1.f / (1.f + __expf(-cwc));
            float* op = out + ((size_t)t * kHQ + h) * kD + l15;
            #pragma unroll
            for (int n8 = 0; n8 < 8; ++n8) {
                const float wM = (oswa[n8][r] * c0 + b2f(ox1[lane * 32 + n8 * 4 + r]) * c1) * li;
                op[n8 * 16] += w2 * wM;
            }
        }
    }
}

// ---------------------------------------------------------------------
extern "C" void kernel_launch(void* const* d_in, const int* in_sizes, int n_in,
                              void* d_out, int out_size, void* d_ws, size_t ws_size,
                              hipStream_t stream) {
    const float* q  = (const float*)d_in[0];
    const float* k  = (const float*)d_in[1];
    const float* v  = (const float*)d_in[2];
    const float* cw = (const float*)d_in[3];
    float* out = (float*)d_out;

    short* kb2    = (short*)d_ws;                         // 32*1024*8 shorts (512 KB)
    _Float16* vt2 = (_Float16*)(kb2 + 32 * 1024 * 8);     // 512 KB
    short* ck2h   = (short*)(vt2 + 32 * 1024 * 8);        // 32 KB
    short* ck2l   = ck2h + 32 * 64 * 8;                   // 32 KB
    short* cv2    = ck2l + 32 * 64 * 8;                   // 32 KB

    k_stage<<<dim3(128), dim3(256), 0, stream>>>(k, v, kb2, vt2, ck2h, ck2l, cv2);
    k_nsa<<<dim3(kT), dim3(128), 0, stream>>>(q, cw, ck2h, ck2l, cv2, kb2, vt2, out);
}

// Round 13
// 158.516 us; speedup vs baseline: 2.4323x; 2.4323x over previous
//
#include <hip/hip_runtime.h>
#include <math.h>

// ---- NSA hyperparameters (compile-time, matches reference config) ----
constexpr int kT    = 2048;
constexpr int kHQ   = 16;
constexpr int kD    = 128;
constexpr int kKS   = 32;
constexpr int kST   = 16;
constexpr int kBS   = 64;
constexpr int kM    = (kT - kKS) / kST + 1;   // 127 compressed tokens
constexpr int kNB   = (kT + kBS - 1) / kBS;   // 32 selection blocks
constexpr int kTopN = 16;
constexpr int kNInit = 2;
constexpr int kWIN  = 512;
constexpr float kNEG = -1e30f;
constexpr float kScale = 0.08838834764831845f;      // 128^-0.5
// log2-domain scores: fold log2(e) into q scaling -> bare exp2 everywhere
constexpr float kScaleL2 = kScale * 1.4426950408889634f;

constexpr int kPSt = 72;    // P slab row stride (fp16)
constexpr int kPL  = 136;   // Phase-A p_lds row stride (bf16 shorts)

// ---- shm layout (bytes).  Phase-A p_lds (4352B) overlays PS0+PS1 (dead
// until pass 1).  dump+ml are the wave1->wave0 exchange, reused for the
// sel merge (pass-1 boundary) then the swa merge (post pass 2).
constexpr int kPS0 = 0;      // 2304: wave0 P slab
constexpr int kPS1 = 2304;   // 2304: wave1 P slab
constexpr int kDmp = 4608;   // 4096: osel/oswa exchange (wave1 partials)
constexpr int kMl  = 8704;   // 128: 16 heads x float2 (m,l)
constexpr int kShm = 8832;

typedef __attribute__((ext_vector_type(8))) short short8;
typedef __attribute__((ext_vector_type(4))) short short4v;
typedef __attribute__((ext_vector_type(8))) _Float16 half8;
typedef __attribute__((ext_vector_type(4))) _Float16 half4v;
typedef __attribute__((ext_vector_type(4))) float floatx4;

// RNE float -> bf16 bits
__device__ inline short f2bf(float x) {
    unsigned u = __float_as_uint(x);
    unsigned r = (u + 0x7fffu + ((u >> 16) & 1u)) >> 16;
    return (short)r;
}
__device__ inline float b2f(short h) {
    return __uint_as_float(((unsigned)(unsigned short)h) << 16);
}

// ---------------------------------------------------------------------
// K1: FRAGMENT-ORDERED staging (R9-proven, unchanged).
// ---------------------------------------------------------------------
__global__ __launch_bounds__(256) void k_stage(
        const float* __restrict__ k, const float* __restrict__ v,
        short* __restrict__ kb2, _Float16* __restrict__ vt2,
        short* __restrict__ ck2h, short* __restrict__ ck2l,
        short* __restrict__ cv2) {
    const int bid = blockIdx.x;
    const int tid = threadIdx.x;
    __shared__ _Float16 vls[64 * 132];

    if (bid < 32) {
        const int b = bid;
        #pragma unroll
        for (int p = 0; p < 4; ++p) {
            const int idx = p * 256 + tid;          // 0..1023 = g*64 + lane
            const int g = idx >> 6;                  // kt*4 + c
            const int lane2 = idx & 63;
            const int kt = g >> 2, c = g & 3;
            const int l15v = lane2 & 15, quadv = lane2 >> 4;
            const float* src = k + (size_t)(b * 64 + kt * 16 + l15v) * kD + c * 32 + quadv * 8;
            const float4 f0 = *(const float4*)(src);
            const float4 f1 = *(const float4*)(src + 4);
            short8 s;
            s[0] = f2bf(f0.x); s[1] = f2bf(f0.y); s[2] = f2bf(f0.z); s[3] = f2bf(f0.w);
            s[4] = f2bf(f1.x); s[5] = f2bf(f1.y); s[6] = f2bf(f1.z); s[7] = f2bf(f1.w);
            *(short8*)(kb2 + ((size_t)b * 1024 + idx) * 8) = s;
        }
    } else if (bid < 64) {
        const int b = bid - 32;
        #pragma unroll
        for (int p = 0; p < 8; ++p) {
            const int idx = p * 256 + tid;   // 2048 float4-slots
            const int r = idx >> 5;
            const int d4 = (idx & 31) * 4;
            const float4 f = *(const float4*)(v + (size_t)(b * 64 + r) * kD + d4);
            _Float16* dst = &vls[r * 132 + d4];
            dst[0] = (_Float16)f.x; dst[1] = (_Float16)f.y;
            dst[2] = (_Float16)f.z; dst[3] = (_Float16)f.w;
        }
        __syncthreads();
        #pragma unroll
        for (int p = 0; p < 4; ++p) {
            const int idx = p * 256 + tid;   // g*64 + lane
            const int g = idx >> 6;          // n8*2 + kc
            const int lane2 = idx & 63;
            const int n8 = g >> 1, kc = g & 1;
            const int l15v = lane2 & 15, quadv = lane2 >> 4;
            half8 h;
            #pragma unroll
            for (int j = 0; j < 8; ++j) {
                const int col = kc * 32 + quadv * 8 + j;
                const int w = (col & 3) * 16 + (col >> 2);
                h[j] = vls[w * 132 + n8 * 16 + l15v];
            }
            *(half8*)(vt2 + ((size_t)b * 1024 + idx) * 8) = h;
        }
    } else {
        const int m = (bid - 64) * 2 + (tid >> 7);   // 0..127
        const int d = tid & 127;
        float sk = 0.f, sv = 0.f;
        if (m < kM) {
            const int base = m * kST;
            #pragma unroll
            for (int i = 0; i < kKS; ++i) {
                sk += k[(size_t)(base + i) * kD + d];
                sv += v[(size_t)(base + i) * kD + d];
            }
            sk *= (1.0f / kKS);
            sv *= (1.0f / kKS);
        }
        const short hi = f2bf(sk);
        const short lo = f2bf(sk - b2f(hi));
        const int mt = m >> 4, l15m = m & 15;
        const int c = d >> 5, quadv = (d >> 3) & 3, j = d & 7;
        const int kdst = ((mt * 4 + c) * 64 + quadv * 16 + l15m) * 8 + j;
        ck2h[kdst] = hi;
        ck2l[kdst] = lo;
        const int nt = d >> 4, l15d = d & 15;
        const int pc = (m & 64) + 4 * (m & 15) + ((m & 63) >> 4);
        const int cp = pc >> 5, quadp = (pc >> 3) & 3, jp = pc & 7;
        cv2[((nt * 4 + cp) * 64 + quadp * 16 + l15d) * 8 + jp] = f2bf(sv);
    }
}

// ---------------------------------------------------------------------
// Fused NSA, 2 waves/query (block=128, grid=T, t=2047-bid).
// R13 = R12's LDS diet (9.2KB: merge-to-global, no ocst/oxS parking)
// with the launch bound REVERTED to (128,4).  Ledger: (128,4)->VGPR 64,
// (128,8)->VGPR 32 + 600MB scratch (R12 disaster).  HW occupancy comes
// from the ACTUAL VGPR count: 64 VGPR allows 8 waves/SIMD; 9.2KB LDS
// allows 16 blocks/CU (147KB<160KB).  The declaration must merely not
// prevent it.
// ---------------------------------------------------------------------
__global__ __launch_bounds__(128, 4) void k_nsa(
        const float* __restrict__ q, const float* __restrict__ cw,
        const short* __restrict__ ck2h, const short* __restrict__ ck2l,
        const short* __restrict__ cv2, const short* __restrict__ kb2,
        const _Float16* __restrict__ vt2, float* __restrict__ out) {
    const int tid = threadIdx.x;
    const int wave = tid >> 6;
    const int lane = tid & 63;
    const int l15 = lane & 15;
    const int quad = lane >> 4;
    const int t = kT - 1 - blockIdx.x;   // LPT: heavy first

    __shared__ float sp[kNB];
    __shared__ unsigned selm_s;
    __shared__ __align__(16) char shm[kShm];

    _Float16* const PSme = (_Float16*)(shm + (wave ? kPS1 : kPS0));

    // ---- q head=l15, scaled by kScale*log2e -> bf16 hi (both waves) ----
    short8 qh[4];
    {
        const float* qp = q + ((size_t)t * kHQ + l15) * kD + quad * 8;
        #pragma unroll
        for (int c = 0; c < 4; ++c) {
            const float4 f0 = *(const float4*)(qp + c * 32);
            const float4 f1 = *(const float4*)(qp + c * 32 + 4);
            const float xs[8] = {f0.x, f0.y, f0.z, f0.w, f1.x, f1.y, f1.z, f1.w};
            #pragma unroll
            for (int j = 0; j < 8; ++j) qh[c][j] = f2bf(xs[j] * kScaleL2);
        }
    }

    const int nvalid = (t >= kKS - 1) ? min(kM, (t - (kKS - 1)) / kST + 1) : 0;
    const int cur = t >> 6;

    // ================= Phase A (wave0 only), log2-domain =================
    if (wave == 0) {
        // lo-half of q built locally (dies with Phase A)
        short8 ql[4];
        {
            const float* qp = q + ((size_t)t * kHQ + l15) * kD + quad * 8;
            #pragma unroll
            for (int c = 0; c < 4; ++c) {
                const float4 f0 = *(const float4*)(qp + c * 32);
                const float4 f1 = *(const float4*)(qp + c * 32 + 4);
                const float xs[8] = {f0.x, f0.y, f0.z, f0.w, f1.x, f1.y, f1.z, f1.w};
                #pragma unroll
                for (int j = 0; j < 8; ++j)
                    ql[c][j] = f2bf(xs[j] * kScaleL2 - b2f(qh[c][j]));
            }
        }
        short* const p_lds = (short*)shm;   // 4352 B, overlays PS0+PS1 (dead)
        floatx4 sacc[8];
        #pragma unroll
        for (int mt = 0; mt < 8; ++mt) {
            sacc[mt] = (floatx4){0, 0, 0, 0};
            #pragma unroll
            for (int c = 0; c < 4; ++c) {
                const short8 Ah = *(const short8*)(ck2h + ((mt * 4 + c) * 64 + lane) * 8);
                const short8 Al = *(const short8*)(ck2l + ((mt * 4 + c) * 64 + lane) * 8);
                sacc[mt] = __builtin_amdgcn_mfma_f32_16x16x32_bf16(Ah, qh[c], sacc[mt], 0, 0, 0);
                sacc[mt] = __builtin_amdgcn_mfma_f32_16x16x32_bf16(Ah, ql[c], sacc[mt], 0, 0, 0);
                sacc[mt] = __builtin_amdgcn_mfma_f32_16x16x32_bf16(Al, qh[c], sacc[mt], 0, 0, 0);
            }
        }
        // mask + max (sacc reused in place: scores -> exps -> probs)
        float mx = kNEG;
        #pragma unroll
        for (int mt = 0; mt < 8; ++mt)
            #pragma unroll
            for (int r = 0; r < 4; ++r) {
                const int m = mt * 16 + quad * 4 + r;
                const float s = (m < nvalid) ? sacc[mt][r] : kNEG;
                sacc[mt][r] = s;
                mx = fmaxf(mx, s);
            }
        mx = fmaxf(mx, __shfl_xor(mx, 16));
        mx = fmaxf(mx, __shfl_xor(mx, 32));
        float sum = 0.f;
        #pragma unroll
        for (int mt = 0; mt < 8; ++mt)
            #pragma unroll
            for (int r = 0; r < 4; ++r) {
                const int m = mt * 16 + quad * 4 + r;
                const float ev = (m < nvalid) ? exp2f(sacc[mt][r] - mx) : 0.f;
                sacc[mt][r] = ev;
                sum += ev;
            }
        sum += __shfl_xor(sum, 16);
        sum += __shfl_xor(sum, 32);
        const float inv = (nvalid > 0) ? (1.f / sum) : 0.f;

        float Z[8], Y[8];
        #pragma unroll
        for (int mt = 0; mt < 8; ++mt) {
            const float p0 = sacc[mt][0] * inv, p1 = sacc[mt][1] * inv;
            const float p2 = sacc[mt][2] * inv, p3 = sacc[mt][3] * inv;
            sacc[mt][0] = p0; sacc[mt][1] = p1; sacc[mt][2] = p2; sacc[mt][3] = p3;
            Z[mt] = p0 + p1 + p2 + 0.5f * p3;
            Y[mt] = p3;
        }
        #pragma unroll
        for (int g = 0; g < 2; ++g)
            #pragma unroll
            for (int r = 0; r < 4; ++r) {
                short4v s4;
                s4[0] = f2bf(sacc[4 * g + 0][r]); s4[1] = f2bf(sacc[4 * g + 1][r]);
                s4[2] = f2bf(sacc[4 * g + 2][r]); s4[3] = f2bf(sacc[4 * g + 3][r]);
                *(short4v*)&p_lds[l15 * kPL + g * 64 + 16 * quad + 4 * r] = s4;
            }
        #pragma unroll
        for (int mt = 0; mt < 8; ++mt) {
            #pragma unroll
            for (int o = 1; o <= 8; o <<= 1) {
                Z[mt] += __shfl_xor(Z[mt], o, 16);
                Y[mt] += __shfl_xor(Y[mt], o, 16);
            }
        }
        const int srcl = ((quad + 3) & 3) * 16 + l15;
        #pragma unroll
        for (int mt = 0; mt < 8; ++mt) {
            const float up  = __shfl(Y[mt], srcl);
            const float upm = __shfl(Y[(mt + 7) & 7], srcl);
            const float pv = quad ? up : (mt ? upm : 0.f);
            const int b = 4 * mt + quad;
            float x = Z[mt] + 0.5f * pv;
            if (b > cur) x = kNEG;
            if (b < kNInit || b == cur) x = 1e30f;
            if (l15 == 0) sp[b] = x;
        }
        bool selp = false;
        if (lane < kNB) {
            const float xv = sp[lane];
            int rank = 0;
            #pragma unroll
            for (int b2 = 0; b2 < kNB; ++b2) {
                const float y = sp[b2];
                rank += (y > xv || (y == xv && b2 < lane)) ? 1 : 0;
            }
            selp = rank < kTopN;
        }
        const unsigned sm = (unsigned)__ballot(selp);
        if (lane == 0) selm_s = sm;

        // cmp PV -> out = w0*ocmp directly (no LDS stash; same-wave RMW later)
        short8 ap[4];
        #pragma unroll
        for (int c = 0; c < 4; ++c)
            ap[c] = *(const short8*)&p_lds[l15 * kPL + c * 32 + quad * 8];
        float w0h[4];
        #pragma unroll
        for (int r = 0; r < 4; ++r) {
            const int h = quad * 4 + r;
            const float cwa = cw[((size_t)t * kHQ + h) * 3 + 0];
            w0h[r] = 1.f / (1.f + __expf(-cwa));
        }
        #pragma unroll
        for (int nt = 0; nt < 8; ++nt) {
            floatx4 oc = (floatx4){0, 0, 0, 0};
            #pragma unroll
            for (int c = 0; c < 4; ++c) {
                const short8 bv = *(const short8*)(cv2 + ((nt * 4 + c) * 64 + lane) * 8);
                oc = __builtin_amdgcn_mfma_f32_16x16x32_bf16(ap[c], bv, oc, 0, 0, 0);
            }
            #pragma unroll
            for (int r = 0; r < 4; ++r) {
                const int h = quad * 4 + r;
                out[((size_t)t * kHQ + h) * kD + nt * 16 + l15] = w0h[r] * oc[r];
            }
        }
    }
    __syncthreads();   // bar0: selm visible; Phase-A LDS dead before slabs reuse

    const unsigned selm = selm_s;
    const int lob = max(0, (t - (kWIN - 1)) >> 6);
    const unsigned lm = 0xFFFFFFFFu >> (31 - cur);

    // ================== PASS 1: SEL (osel in regs) ==================
    {
        float mS = kNEG, lS = 0.f;
        floatx4 osel[8];
        #pragma unroll
        for (int n8 = 0; n8 < 8; ++n8) osel[n8] = (floatx4){0, 0, 0, 0};

        unsigned a = selm & lm;
        int bi = 0;
        while (a) {
            const int b = __builtin_ctz(a);
            a &= a - 1u;
            const bool mine = ((bi & 1) != wave);
            ++bi;
            if (!mine) continue;

            const short* kbb = kb2 + ((size_t)b * 1024 + lane) * 8;
            floatx4 acc[4];
            {
                short8 kreg[2][4];
                #pragma unroll
                for (int kt = 0; kt < 2; ++kt)
                    #pragma unroll
                    for (int c = 0; c < 4; ++c)
                        kreg[kt][c] = *(const short8*)(kbb + (kt * 4 + c) * 512);
                #pragma unroll
                for (int kt = 0; kt < 2; ++kt) {
                    acc[kt] = (floatx4){0, 0, 0, 0};
                    #pragma unroll
                    for (int c = 0; c < 4; ++c)
                        acc[kt] = __builtin_amdgcn_mfma_f32_16x16x32_bf16(kreg[kt][c], qh[c], acc[kt], 0, 0, 0);
                }
                #pragma unroll
                for (int kt = 0; kt < 2; ++kt)
                    #pragma unroll
                    for (int c = 0; c < 4; ++c)
                        kreg[kt][c] = *(const short8*)(kbb + ((kt + 2) * 4 + c) * 512);
                #pragma unroll
                for (int kt = 0; kt < 2; ++kt) {
                    acc[kt + 2] = (floatx4){0, 0, 0, 0};
                    #pragma unroll
                    for (int c = 0; c < 4; ++c)
                        acc[kt + 2] = __builtin_amdgcn_mfma_f32_16x16x32_bf16(kreg[kt][c], qh[c], acc[kt + 2], 0, 0, 0);
                }
            }

            const int kbo = b * kBS + quad * 4;
            float bm = kNEG;
            #pragma unroll
            for (int kt = 0; kt < 4; ++kt)
                #pragma unroll
                for (int r = 0; r < 4; ++r) {
                    const int key = kbo + kt * 16 + r;
                    if (key <= t) bm = fmaxf(bm, acc[kt][r]);
                }
            bm = fmaxf(bm, __shfl_xor(bm, 16));
            bm = fmaxf(bm, __shfl_xor(bm, 32));
            const float mn = fmaxf(mS, bm);
            const float al = exp2f(mS - mn);

            float sum = 0.f;
            #pragma unroll
            for (int r = 0; r < 4; ++r) {
                half4v hs;
                #pragma unroll
                for (int kt = 0; kt < 4; ++kt) {
                    const int key = kbo + kt * 16 + r;
                    const float e0 = (key <= t) ? exp2f(acc[kt][r] - mn) : 0.f;
                    sum += e0;
                    hs[kt] = (_Float16)e0;
                }
                *(half4v*)&PSme[l15 * kPSt + 16 * quad + 4 * r] = hs;
            }
            sum += __shfl_xor(sum, 16);
            sum += __shfl_xor(sum, 32);
            lS = lS * al + sum; mS = mn;

            float alh[4];
            #pragma unroll
            for (int r = 0; r < 4; ++r) alh[r] = __shfl(al, quad * 4 + r);
            const half8 ap0 = *(const half8*)&PSme[l15 * kPSt + quad * 8];
            const half8 ap1 = *(const half8*)&PSme[l15 * kPSt + 32 + quad * 8];
            const _Float16* vtb = vt2 + ((size_t)b * 1024 + lane) * 8;
            {
                half8 vr[4][2];
                #pragma unroll
                for (int n8 = 0; n8 < 4; ++n8) {
                    vr[n8][0] = *(const half8*)(vtb + (n8 * 2 + 0) * 512);
                    vr[n8][1] = *(const half8*)(vtb + (n8 * 2 + 1) * 512);
                }
                #pragma unroll
                for (int n8 = 0; n8 < 4; ++n8) {
                    #pragma unroll
                    for (int r = 0; r < 4; ++r) osel[n8][r] *= alh[r];
                    osel[n8] = __builtin_amdgcn_mfma_f32_16x16x32_f16(ap0, vr[n8][0], osel[n8], 0, 0, 0);
                    osel[n8] = __builtin_amdgcn_mfma_f32_16x16x32_f16(ap1, vr[n8][1], osel[n8], 0, 0, 0);
                }
                #pragma unroll
                for (int n8 = 0; n8 < 4; ++n8) {
                    vr[n8][0] = *(const half8*)(vtb + ((n8 + 4) * 2 + 0) * 512);
                    vr[n8][1] = *(const half8*)(vtb + ((n8 + 4) * 2 + 1) * 512);
                }
                #pragma unroll
                for (int n8 = 0; n8 < 4; ++n8) {
                    #pragma unroll
                    for (int r = 0; r < 4; ++r) osel[n8 + 4][r] *= alh[r];
                    osel[n8 + 4] = __builtin_amdgcn_mfma_f32_16x16x32_f16(ap0, vr[n8][0], osel[n8 + 4], 0, 0, 0);
                    osel[n8 + 4] = __builtin_amdgcn_mfma_f32_16x16x32_f16(ap1, vr[n8][1], osel[n8 + 4], 0, 0, 0);
                }
            }
        }

        // ---- SEL exchange + merge (dump region freed before pass-2 use) ----
        if (wave == 1) {
            short* const dmp = (short*)(shm + kDmp);
            #pragma unroll
            for (int n8 = 0; n8 < 8; ++n8) {
                short4v s4;
                #pragma unroll
                for (int r = 0; r < 4; ++r) s4[r] = f2bf(osel[n8][r]);
                *(short4v*)&dmp[lane * 32 + n8 * 4] = s4;
            }
            if (quad == 0) ((float2*)(shm + kMl))[l15] = make_float2(mS, lS);
        }
        __syncthreads();   // barA: wave1 partials visible
        if (wave == 0) {
            const short* const ox1 = (const short*)(shm + kDmp);
            const float2* const ml1 = (const float2*)(shm + kMl);
            #pragma unroll
            for (int r = 0; r < 4; ++r) {
                const int h = quad * 4 + r;
                const float m0 = __shfl(mS, h), l0 = __shfl(lS, h);
                const float2 s1 = ml1[h];
                const float mM = fmaxf(m0, s1.x);
                const float c0 = exp2f(m0 - mM);
                const float c1 = exp2f(s1.x - mM);
                const float li = 1.f / (l0 * c0 + s1.y * c1);
                const float cwb = cw[((size_t)t * kHQ + h) * 3 + 1];
                const float w1 = 1.f / (1.f + __expf(-cwb));
                float* op = out + ((size_t)t * kHQ + h) * kD + l15;
                #pragma unroll
                for (int n8 = 0; n8 < 8; ++n8) {
                    const float sM = (osel[n8][r] * c0 + b2f(ox1[lane * 32 + n8 * 4 + r]) * c1) * li;
                    op[n8 * 16] += w1 * sM;
                }
            }
        }
    }

    // ================== PASS 2: SWA (oswa in regs) ==================
    float mW = kNEG, lW = 0.f;
    floatx4 oswa[8];
    #pragma unroll
    for (int n8 = 0; n8 < 8; ++n8) oswa[n8] = (floatx4){0, 0, 0, 0};
    {
        unsigned a = lm & ~((1u << lob) - 1u);
        int bi = 0;
        while (a) {
            const int b = __builtin_ctz(a);
            a &= a - 1u;
            const bool mine = ((bi & 1) != wave);
            ++bi;
            if (!mine) continue;

            const short* kbb = kb2 + ((size_t)b * 1024 + lane) * 8;
            floatx4 acc[4];
            {
                short8 kreg[2][4];
                #pragma unroll
                for (int kt = 0; kt < 2; ++kt)
                    #pragma unroll
                    for (int c = 0; c < 4; ++c)
                        kreg[kt][c] = *(const short8*)(kbb + (kt * 4 + c) * 512);
                #pragma unroll
                for (int kt = 0; kt < 2; ++kt) {
                    acc[kt] = (floatx4){0, 0, 0, 0};
                    #pragma unroll
                    for (int c = 0; c < 4; ++c)
                        acc[kt] = __builtin_amdgcn_mfma_f32_16x16x32_bf16(kreg[kt][c], qh[c], acc[kt], 0, 0, 0);
                }
                #pragma unroll
                for (int kt = 0; kt < 2; ++kt)
                    #pragma unroll
                    for (int c = 0; c < 4; ++c)
                        kreg[kt][c] = *(const short8*)(kbb + ((kt + 2) * 4 + c) * 512);
                #pragma unroll
                for (int kt = 0; kt < 2; ++kt) {
                    acc[kt + 2] = (floatx4){0, 0, 0, 0};
                    #pragma unroll
                    for (int c = 0; c < 4; ++c)
                        acc[kt + 2] = __builtin_amdgcn_mfma_f32_16x16x32_bf16(kreg[kt][c], qh[c], acc[kt + 2], 0, 0, 0);
                }
            }

            const int kbo = b * kBS + quad * 4;
            float bm = kNEG;
            #pragma unroll
            for (int kt = 0; kt < 4; ++kt)
                #pragma unroll
                for (int r = 0; r < 4; ++r) {
                    const int key = kbo + kt * 16 + r;
                    if (key <= t && (t - key) < kWIN) bm = fmaxf(bm, acc[kt][r]);
                }
            bm = fmaxf(bm, __shfl_xor(bm, 16));
            bm = fmaxf(bm, __shfl_xor(bm, 32));
            const float mn = fmaxf(mW, bm);
            const float al = exp2f(mW - mn);

            float sum = 0.f;
            #pragma unroll
            for (int r = 0; r < 4; ++r) {
                half4v hw;
                #pragma unroll
                for (int kt = 0; kt < 4; ++kt) {
                    const int key = kbo + kt * 16 + r;
                    const float e0 = (key <= t && (t - key) < kWIN) ? exp2f(acc[kt][r] - mn) : 0.f;
                    sum += e0;
                    hw[kt] = (_Float16)e0;
                }
                *(half4v*)&PSme[l15 * kPSt + 16 * quad + 4 * r] = hw;
            }
            sum += __shfl_xor(sum, 16);
            sum += __shfl_xor(sum, 32);
            lW = lW * al + sum; mW = mn;

            float alh[4];
            #pragma unroll
            for (int r = 0; r < 4; ++r) alh[r] = __shfl(al, quad * 4 + r);
            const half8 ap0 = *(const half8*)&PSme[l15 * kPSt + quad * 8];
            const half8 ap1 = *(const half8*)&PSme[l15 * kPSt + 32 + quad * 8];
            const _Float16* vtb = vt2 + ((size_t)b * 1024 + lane) * 8;
            {
                half8 vr[4][2];
                #pragma unroll
                for (int n8 = 0; n8 < 4; ++n8) {
                    vr[n8][0] = *(const half8*)(vtb + (n8 * 2 + 0) * 512);
                    vr[n8][1] = *(const half8*)(vtb + (n8 * 2 + 1) * 512);
                }
                #pragma unroll
                for (int n8 = 0; n8 < 4; ++n8) {
                    #pragma unroll
                    for (int r = 0; r < 4; ++r) oswa[n8][r] *= alh[r];
                    oswa[n8] = __builtin_amdgcn_mfma_f32_16x16x32_f16(ap0, vr[n8][0], oswa[n8], 0, 0, 0);
                    oswa[n8] = __builtin_amdgcn_mfma_f32_16x16x32_f16(ap1, vr[n8][1], oswa[n8], 0, 0, 0);
                }
                #pragma unroll
                for (int n8 = 0; n8 < 4; ++n8) {
                    vr[n8][0] = *(const half8*)(vtb + ((n8 + 4) * 2 + 0) * 512);
                    vr[n8][1] = *(const half8*)(vtb + ((n8 + 4) * 2 + 1) * 512);
                }
                #pragma unroll
                for (int n8 = 0; n8 < 4; ++n8) {
                    #pragma unroll
                    for (int r = 0; r < 4; ++r) oswa[n8 + 4][r] *= alh[r];
                    oswa[n8 + 4] = __builtin_amdgcn_mfma_f32_16x16x32_f16(ap0, vr[n8][0], oswa[n8 + 4], 0, 0, 0);
                    oswa[n8 + 4] = __builtin_amdgcn_mfma_f32_16x16x32_f16(ap1, vr[n8][1], oswa[n8 + 4], 0, 0, 0);
                }
            }
        }
    }

    __syncthreads();   // barB: both pass-2 done; wave0's sel reads long done
    if (wave == 1) {
        short* const dmp = (short*)(shm + kDmp);
        #pragma unroll
        for (int n8 = 0; n8 < 8; ++n8) {
            short4v w4;
            #pragma unroll
            for (int r = 0; r < 4; ++r) w4[r] = f2bf(oswa[n8][r]);
            *(short4v*)&dmp[lane * 32 + n8 * 4] = w4;
        }
        if (quad == 0) ((float2*)(shm + kMl))[l15] = make_float2(mW, lW);
    }
    __syncthreads();   // barC: wave1 swa partials visible
    if (wave == 0) {
        const short* const ox1 = (const short*)(shm + kDmp);
        const float2* const ml1 = (const float2*)(shm + kMl);
        #pragma unroll
        for (int r = 0; r < 4; ++r) {
            const int h = quad * 4 + r;
            const float m0 = __shfl(mW, h), l0 = __shfl(lW, h);
            const float2 s1 = ml1[h];
            const float mM = fmaxf(m0, s1.x);
            const float c0 = exp2f(m0 - mM);
            const float c1 = exp2f(s1.x - mM);
            const float li = 1.f / (l0 * c0 + s1.y * c1);
            const float cwc = cw[((size_t)t * kHQ + h) * 3 + 2];
            const float w2 = 1.f / (1.f + __expf(-cwc));
            float* op = out + ((size_t)t * kHQ + h) * kD + l15;
            #pragma unroll
            for (int n8 = 0; n8 < 8; ++n8) {
                const float wM = (oswa[n8][r] * c0 + b2f(ox1[lane * 32 + n8 * 4 + r]) * c1) * li;
                op[n8 * 16] += w2 * wM;
            }
        }
    }
}

// ---------------------------------------------------------------------
extern "C" void kernel_launch(void* const* d_in, const int* in_sizes, int n_in,
                              void* d_out, int out_size, void* d_ws, size_t ws_size,
                              hipStream_t stream) {
    const float* q  = (const float*)d_in[0];
    const float* k  = (const float*)d_in[1];
    const float* v  = (const float*)d_in[2];
    const float* cw = (const float*)d_in[3];
    float* out = (float*)d_out;

    short* kb2    = (short*)d_ws;                         // 32*1024*8 shorts (512 KB)
    _Float16* vt2 = (_Float16*)(kb2 + 32 * 1024 * 8);     // 512 KB
    short* ck2h   = (short*)(vt2 + 32 * 1024 * 8);        // 32 KB
    short* ck2l   = ck2h + 32 * 64 * 8;                   // 32 KB
    short* cv2    = ck2l + 32 * 64 * 8;                   // 32 KB

    k_stage<<<dim3(128), dim3(256), 0, stream>>>(k, v, kb2, vt2, ck2h, ck2l, cv2);
    k_nsa<<<dim3(kT), dim3(128), 0, stream>>>(q, cw, ck2h, ck2l, cv2, kb2, vt2, out);
}